// Round 9
// baseline (155.381 us; speedup 1.0000x reference)
//
#include <hip/hip_runtime.h>

#define N_NODES 100000
#define N_EDGES 800000
#define IN_SIZE 128
#define OUT_SIZE 64

#define GEMM_BLOCKS 1563   // ceil(6250 tiles / 4 waves-per-block): 1 tile/wave
#define RP_BLOCKS   128
#define N_TILES     (N_NODES / 16)   // 6250 exact
#define PROP_BLOCKS ((N_NODES + 63) / 64)  // 64 nodes/block, 4 lanes/node

typedef __attribute__((ext_vector_type(8))) short short8;
typedef __attribute__((ext_vector_type(4))) float f32x4;

__device__ __forceinline__ unsigned short f2bf(float x) {
    unsigned u = __float_as_uint(x);
    u += 0x7FFFu + ((u >> 16) & 1u);          // round-to-nearest-even
    return (unsigned short)(u >> 16);
}

// int8 row layout (both H buffers): row = 16 dwords; dword d's byte b holds
// channel (d + 16*b), stored BIASED (u = q + 128). Per-row fp32 dequant
// scale in a separate array: val = scale * (u - 128).

// ---------------------------------------------------------------------------
// Kernel 1 (fused): H0 = int8_rowscale(data @ W + b) via MFMA + CSR rowptr.
// Identical math to R7 (passed, absmax 0.0156). Only change: grid 512->1563
// blocks so each wave owns ~1 tile (occupancy 2 -> ~3 blocks/CU; gemm was
// streaming-starved at 8 waves/CU).
// ---------------------------------------------------------------------------
__global__ __launch_bounds__(256) void gemm_rowptr_kernel(
    const float* __restrict__ data, const float* __restrict__ W,
    const float* __restrict__ b, const int* __restrict__ tgt,
    uint4* __restrict__ H, float* __restrict__ Hs, int* __restrict__ rowptr)
{
    if (blockIdx.x >= GEMM_BLOCKS) {
        int t = (int)(blockIdx.x - GEMM_BLOCKS) * 256 + (int)threadIdx.x;
        for (; t <= N_NODES; t += RP_BLOCKS * 256) {
            int lo = 0, hi = N_EDGES;
            while (lo < hi) {
                const int mid = (lo + hi) >> 1;
                if (tgt[mid] < t) lo = mid + 1; else hi = mid;
            }
            rowptr[t] = lo;
        }
        return;
    }

    __shared__ unsigned Clds[4][16 * 20];  // per-wave 1280B regions

    const int tid  = threadIdx.x;
    const int lane = tid & 63;
    const int wv   = tid >> 6;
    const int quad = lane >> 4;
    const int col  = lane & 15;

    union U8 { short8 v; unsigned short u[8]; };

    // B fragments from global W (fp32 -> bf16); B[k=quad*8+j][n=nt*16+col]
    short8 wb[4][4];
    #pragma unroll
    for (int kc = 0; kc < 4; ++kc) {
        #pragma unroll
        for (int nt = 0; nt < 4; ++nt) {
            U8 t;
            #pragma unroll
            for (int j = 0; j < 8; ++j) {
                const int k = kc * 32 + quad * 8 + j;
                t.u[j] = f2bf(W[k * OUT_SIZE + nt * 16 + col]);
            }
            wb[kc][nt] = t.v;
        }
    }
    float bcol[4];
    #pragma unroll
    for (int nt = 0; nt < 4; ++nt) bcol[nt] = b[nt * 16 + col];

    unsigned* cl = Clds[wv];

    for (int tile = blockIdx.x * 4 + wv; tile < N_TILES;
         tile += GEMM_BLOCKS * 4) {
        const int r0 = tile * 16;
        const float* arow = data + (size_t)(r0 + col) * IN_SIZE + quad * 8;

        short8 af[4];
        #pragma unroll
        for (int kc = 0; kc < 4; ++kc) {
            const float4 x0 = *(const float4*)(arow + kc * 32);
            const float4 x1 = *(const float4*)(arow + kc * 32 + 4);
            U8 t;
            t.u[0] = f2bf(x0.x); t.u[1] = f2bf(x0.y);
            t.u[2] = f2bf(x0.z); t.u[3] = f2bf(x0.w);
            t.u[4] = f2bf(x1.x); t.u[5] = f2bf(x1.y);
            t.u[6] = f2bf(x1.z); t.u[7] = f2bf(x1.w);
            af[kc] = t.v;
        }

        f32x4 acc[4];
        #pragma unroll
        for (int nt = 0; nt < 4; ++nt) acc[nt] = (f32x4){0.f, 0.f, 0.f, 0.f};
        #pragma unroll
        for (int kc = 0; kc < 4; ++kc) {
            #pragma unroll
            for (int nt = 0; nt < 4; ++nt)
                acc[nt] = __builtin_amdgcn_mfma_f32_16x16x32_bf16(
                    af[kc], wb[kc][nt], acc[nt], 0, 0, 0);
        }

        // epilogue: +bias, per-row absmax, biased-uint8 quantize
        // C/D layout: channel nt*16+col, row quad*4+reg
        float v[4][4];   // [nt][r]
        #pragma unroll
        for (int nt = 0; nt < 4; ++nt)
            #pragma unroll
            for (int r = 0; r < 4; ++r)
                v[nt][r] = acc[nt][r] + bcol[nt];

        float rmax[4];
        #pragma unroll
        for (int r = 0; r < 4; ++r) {
            float m = fabsf(v[0][r]);
            m = fmaxf(m, fabsf(v[1][r]));
            m = fmaxf(m, fabsf(v[2][r]));
            m = fmaxf(m, fabsf(v[3][r]));
            m = fmaxf(m, __shfl_xor(m, 1, 64));
            m = fmaxf(m, __shfl_xor(m, 2, 64));
            m = fmaxf(m, __shfl_xor(m, 4, 64));
            m = fmaxf(m, __shfl_xor(m, 8, 64));
            rmax[r] = m;
        }
        if (col < 4)
            Hs[r0 + quad * 4 + col] = rmax[col] * (1.f / 127.f);

        #pragma unroll
        for (int r = 0; r < 4; ++r) {
            const float inv = rmax[r] > 0.f ? 127.f / rmax[r] : 0.f;
            const unsigned u0 = (unsigned)(int)rintf(v[0][r] * inv + 128.f);
            const unsigned u1 = (unsigned)(int)rintf(v[1][r] * inv + 128.f);
            const unsigned u2 = (unsigned)(int)rintf(v[2][r] * inv + 128.f);
            const unsigned u3 = (unsigned)(int)rintf(v[3][r] * inv + 128.f);
            cl[(quad * 4 + r) * 20 + col] =
                u0 | (u1 << 8) | (u2 << 16) | (u3 << 24);
        }

        // transpose readback (wave-private LDS, no barrier): 64B row stores
        {
            const int row = lane >> 2;
            const int seg = lane & 3;
            const uint4 vv = *(const uint4*)(cl + row * 20 + seg * 4);
            H[(size_t)(r0 + row) * 4 + seg] = vv;
        }
    }
}

// ---------------------------------------------------------------------------
// Kernel 2/3: one propagation round on int8 per-row-scale rows (64B/row).
// out[t] = (in[t] + sum in[src_e]) / (deg+1); 0 if deg==0.
// 4-lane subgroup per node; branchless 8-edge batches (invalid slots clamp
// to edge0, scale weight 0). Biased trick: acc += c_j*u; sumS += c_j;
// val = (acc - 128*sumS)/(deg+1).
// Regime note (R4-R7 evidence): random row gathers cost one 128B LLC line
// per edge regardless of row size -> ~102MB line traffic/round @ ~3.4TB/s
// ~ 30us/round. This is the structural ceiling for this kernel.
// ---------------------------------------------------------------------------
#define ACC16(vv, c)                                                        \
    {                                                                        \
        const unsigned* _w = (const unsigned*)&(vv);                         \
        _Pragma("unroll")                                                    \
        for (int _d = 0; _d < 4; ++_d) {                                     \
            _Pragma("unroll")                                                \
            for (int _b = 0; _b < 4; ++_b)                                   \
                acc[_d * 4 + _b] = fmaf(                                     \
                    (float)((_w[_d] >> (8 * _b)) & 255u), (c), acc[_d*4+_b]);\
        }                                                                    \
    }

template <bool FINAL>
__global__ __launch_bounds__(256) void prop_kernel(
    const uint4* __restrict__ inq, const float* __restrict__ insc,
    void* __restrict__ outp, float* __restrict__ outsc,
    const int* __restrict__ rowptr, const int* __restrict__ src)
{
    const int tid   = threadIdx.x;
    const int lane  = tid & 63;
    const int s     = lane & 3;     // 16B chunk (dwords s*4..s*4+3)
    const int lbase = lane & 60;    // subgroup base lane
    const int noder = blockIdx.x * 64 + (tid >> 2);
    const bool valid = noder < N_NODES;
    const int node  = valid ? noder : N_NODES - 1;

    const int start = rowptr[node];
    const int end   = rowptr[node + 1];
    const int deg   = end - start;

    const uint4 ownq = inq[(size_t)node * 4 + s];
    const float owns = insc[node];

    float acc[16];
    #pragma unroll
    for (int k = 0; k < 16; ++k) acc[k] = 0.f;
    float sumS = 0.f;

    if (deg > 0) {
        for (int base = start; base < end; base += 8) {
            const int rem = end - base;
            const int liA = base + s;
            const int svA = src[liA < end ? liA : base];
            int svB = 0;
            if (base + 4 < end) {
                const int liB = base + 4 + s;
                svB = src[liB < end ? liB : base + 4];
            }
            const int e0 = __shfl(svA, lbase + 0, 64);
            const int e1 = __shfl(svA, lbase + 1, 64);
            const int e2 = __shfl(svA, lbase + 2, 64);
            const int e3 = __shfl(svA, lbase + 3, 64);
            const int e4 = __shfl(svB, lbase + 0, 64);
            const int e5 = __shfl(svB, lbase + 1, 64);
            const int e6 = __shfl(svB, lbase + 2, 64);
            const int e7 = __shfl(svB, lbase + 3, 64);

            const int i1 = rem > 1 ? e1 : e0;
            const int i2 = rem > 2 ? e2 : e0;
            const int i3 = rem > 3 ? e3 : e0;
            const int i4 = rem > 4 ? e4 : e0;
            const int i5 = rem > 5 ? e5 : e0;
            const int i6 = rem > 6 ? e6 : e0;
            const int i7 = rem > 7 ? e7 : e0;

            const uint4 v0 = inq[(size_t)e0 * 4 + s];
            const uint4 v1 = inq[(size_t)i1 * 4 + s];
            const uint4 v2 = inq[(size_t)i2 * 4 + s];
            const uint4 v3 = inq[(size_t)i3 * 4 + s];
            const uint4 v4 = inq[(size_t)i4 * 4 + s];
            const uint4 v5 = inq[(size_t)i5 * 4 + s];
            const uint4 v6 = inq[(size_t)i6 * 4 + s];
            const uint4 v7 = inq[(size_t)i7 * 4 + s];

            const float c0 = insc[e0];
            const float c1 = rem > 1 ? insc[i1] : 0.f;
            const float c2 = rem > 2 ? insc[i2] : 0.f;
            const float c3 = rem > 3 ? insc[i3] : 0.f;
            const float c4 = rem > 4 ? insc[i4] : 0.f;
            const float c5 = rem > 5 ? insc[i5] : 0.f;
            const float c6 = rem > 6 ? insc[i6] : 0.f;
            const float c7 = rem > 7 ? insc[i7] : 0.f;

            sumS += c0 + c1 + c2 + c3 + c4 + c5 + c6 + c7;
            ACC16(v0, c0); ACC16(v1, c1); ACC16(v2, c2); ACC16(v3, c3);
            ACC16(v4, c4); ACC16(v5, c5); ACC16(v6, c6); ACC16(v7, c7);
        }
        // own contribution
        ACC16(ownq, owns);
        sumS += owns;
    }

    float val[16];
    if (deg == 0) {
        #pragma unroll
        for (int k = 0; k < 16; ++k) val[k] = 0.f;
    } else {
        const float invm  = 1.0f / (float)(deg + 1);
        const float bias  = 128.f * sumS;
        #pragma unroll
        for (int k = 0; k < 16; ++k) {
            val[k] = (acc[k] - bias) * invm;
            if (FINAL) val[k] = fmaxf(val[k], 0.f);
        }
    }

    if (FINAL) {
        // un-permute: channel of val[d*4+b] is (s*4+d) + 16*b
        __shared__ float T[64 * 68];
        const int nl = tid >> 2;
        #pragma unroll
        for (int d = 0; d < 4; ++d)
            #pragma unroll
            for (int bb = 0; bb < 4; ++bb)
                T[nl * 68 + (s * 4 + d) + 16 * bb] = val[d * 4 + bb];
        __syncthreads();
        float* out = (float*)outp;
        const int nb = blockIdx.x * 64;
        #pragma unroll
        for (int p = 0; p < 4; ++p) {
            const int pos = p * 1024 + tid * 4;  // dword index in 64x64 tile
            const int n   = pos >> 6;
            const int ch  = pos & 63;
            if (nb + n < N_NODES) {
                const float4 vv = *(const float4*)(T + n * 68 + ch);
                *(float4*)(out + (size_t)(nb + n) * OUT_SIZE + ch) = vv;
            }
        }
    } else {
        // requantize: row absmax across 16 in-lane + 4-lane subgroup
        float m = 0.f;
        #pragma unroll
        for (int k = 0; k < 16; ++k) m = fmaxf(m, fabsf(val[k]));
        m = fmaxf(m, __shfl_xor(m, 1, 64));
        m = fmaxf(m, __shfl_xor(m, 2, 64));
        const float invq = m > 0.f ? 127.f / m : 0.f;
        uint4 pv;
        unsigned* pw = (unsigned*)&pv;
        #pragma unroll
        for (int d = 0; d < 4; ++d) {
            const unsigned u0 = (unsigned)(int)rintf(val[d * 4 + 0] * invq + 128.f);
            const unsigned u1 = (unsigned)(int)rintf(val[d * 4 + 1] * invq + 128.f);
            const unsigned u2 = (unsigned)(int)rintf(val[d * 4 + 2] * invq + 128.f);
            const unsigned u3 = (unsigned)(int)rintf(val[d * 4 + 3] * invq + 128.f);
            pw[d] = u0 | (u1 << 8) | (u2 << 16) | (u3 << 24);
        }
        if (valid) {
            ((uint4*)outp)[(size_t)node * 4 + s] = pv;
            if (s == 0) outsc[node] = m * (1.f / 127.f);
        }
    }
}

// ---------------------------------------------------------------------------
// Launch
// ---------------------------------------------------------------------------
extern "C" void kernel_launch(void* const* d_in, const int* in_sizes, int n_in,
                              void* d_out, int out_size, void* d_ws, size_t ws_size,
                              hipStream_t stream)
{
    const float* data = (const float*)d_in[0];
    const float* W    = (const float*)d_in[1];
    const float* b    = (const float*)d_in[2];
    const int*   src  = (const int*)d_in[3];
    const int*   tgt  = (const int*)d_in[4];

    // ws: H0 int8 (6.4MB) | H1 int8 (6.4MB) | H0s | H1s | rowptr
    char*  base   = (char*)d_ws;
    uint4* H0     = (uint4*)base;
    uint4* H1     = (uint4*)(base + (size_t)N_NODES * OUT_SIZE);
    float* H0s    = (float*)(base + 2 * (size_t)N_NODES * OUT_SIZE);
    float* H1s    = H0s + N_NODES;
    int*   rowptr = (int*)(H1s + N_NODES);

    gemm_rowptr_kernel<<<GEMM_BLOCKS + RP_BLOCKS, 256, 0, stream>>>(
        data, W, b, tgt, H0, H0s, rowptr);
    prop_kernel<false><<<PROP_BLOCKS, 256, 0, stream>>>(
        H0, H0s, (void*)H1, H1s, rowptr, src);
    prop_kernel<true ><<<PROP_BLOCKS, 256, 0, stream>>>(
        H1, H1s, d_out, nullptr, rowptr, src);
}

// Round 10
// 154.716 us; speedup vs baseline: 1.0043x; 1.0043x over previous
//
#include <hip/hip_runtime.h>

#define N_NODES 100000
#define N_EDGES 800000
#define IN_SIZE 128
#define OUT_SIZE 64

#define GEMM_BLOCKS 1024   // 4 blocks/CU: 4 waves/SIMD TLP for the A stream
#define RP_BLOCKS   128
#define N_TILES     (N_NODES / 16)   // 6250 exact
#define PROP_BLOCKS ((N_NODES + 63) / 64)  // 64 nodes/block, 4 lanes/node
#define WS 136   // Wt LDS stride in bf16 elements (272B rows, 16B-aligned)

typedef __attribute__((ext_vector_type(8))) short short8;
typedef __attribute__((ext_vector_type(4))) float f32x4;

__device__ __forceinline__ unsigned short f2bf(float x) {
    unsigned u = __float_as_uint(x);
    u += 0x7FFFu + ((u >> 16) & 1u);          // round-to-nearest-even
    return (unsigned short)(u >> 16);
}
__device__ __forceinline__ unsigned pack2(float lo, float hi) {
    return (unsigned)f2bf(lo) | ((unsigned)f2bf(hi) << 16);
}

// int8 row layout (both H buffers): row = 16 dwords; dword d's byte b holds
// channel (d + 16*b), stored BIASED (u = q + 128). Per-row fp32 dequant
// scale in a separate array: val = scale * (u - 128).

// ---------------------------------------------------------------------------
// Kernel 1 (fused): H0 = int8_rowscale(data @ W + b) via MFMA + CSR rowptr.
// R10 fix (evidence: R9 VGPR_Count=48 -> compiler rematerialized the 128
// scattered global W loads per TILE): stage W once per block into LDS as
// TRANSPOSED bf16 Wt[n][k] (stride 136: staging ds_write_b32 conflict-free,
// fragment read = one 16B-aligned ds_read_b128 per fragment). Even if the
// compiler sinks fragment reads into the tile loop, they're cheap LDS ops.
// ---------------------------------------------------------------------------
__global__ __launch_bounds__(256) void gemm_rowptr_kernel(
    const float* __restrict__ data, const float* __restrict__ W,
    const float* __restrict__ b, const int* __restrict__ tgt,
    uint4* __restrict__ H, float* __restrict__ Hs, int* __restrict__ rowptr)
{
    if (blockIdx.x >= GEMM_BLOCKS) {
        int t = (int)(blockIdx.x - GEMM_BLOCKS) * 256 + (int)threadIdx.x;
        for (; t <= N_NODES; t += RP_BLOCKS * 256) {
            int lo = 0, hi = N_EDGES;
            while (lo < hi) {
                const int mid = (lo + hi) >> 1;
                if (tgt[mid] < t) lo = mid + 1; else hi = mid;
            }
            rowptr[t] = lo;
        }
        return;
    }

    __shared__ __align__(16) unsigned short Wt[64 * WS];  // 17408 B
    __shared__ unsigned Clds[4][16 * 20];                 //  5120 B

    const int tid  = threadIdx.x;
    const int lane = tid & 63;
    const int wv   = tid >> 6;
    const int quad = lane >> 4;
    const int col  = lane & 15;

    // ---- stage W (fp32 row-major [k][n]) -> LDS bf16 transposed Wt[n][k] ----
    // thread t: k-pair p = t&63 (k = 2p,2p+1), n-quarter h = t>>6.
    // ds_write_b32 banks: dword idx = n*68 + p -> p%32 across the wave: 2-way.
    {
        const int p = tid & 63;
        const int h = tid >> 6;
        const float* w0 = W + (size_t)(2 * p) * OUT_SIZE + h * 16;
        const float* w1 = w0 + OUT_SIZE;
        unsigned* Wt32 = (unsigned*)Wt;
        #pragma unroll
        for (int i = 0; i < 16; ++i)
            Wt32[(h * 16 + i) * (WS / 2) + p] = pack2(w0[i], w1[i]);
    }
    __syncthreads();

    float bcol[4];
    #pragma unroll
    for (int nt = 0; nt < 4; ++nt) bcol[nt] = b[nt * 16 + col];

    // ---- W fragments from LDS: one ds_read_b128 each ----
    // wb[kc][nt][j] = W[k = kc*32+quad*8+j][n = nt*16+col] = Wt[n][k..k+7]
    short8 wb[4][4];
    #pragma unroll
    for (int kc = 0; kc < 4; ++kc)
        #pragma unroll
        for (int nt = 0; nt < 4; ++nt)
            wb[kc][nt] = *(const short8*)(
                Wt + (nt * 16 + col) * WS + kc * 32 + quad * 8);

    union U8 { short8 v; unsigned short u[8]; };
    unsigned* cl = Clds[wv];

    for (int tile = blockIdx.x * 4 + wv; tile < N_TILES;
         tile += GEMM_BLOCKS * 4) {
        const int r0 = tile * 16;
        const float* arow = data + (size_t)(r0 + col) * IN_SIZE + quad * 8;

        short8 af[4];
        #pragma unroll
        for (int kc = 0; kc < 4; ++kc) {
            const float4 x0 = *(const float4*)(arow + kc * 32);
            const float4 x1 = *(const float4*)(arow + kc * 32 + 4);
            U8 t;
            t.u[0] = f2bf(x0.x); t.u[1] = f2bf(x0.y);
            t.u[2] = f2bf(x0.z); t.u[3] = f2bf(x0.w);
            t.u[4] = f2bf(x1.x); t.u[5] = f2bf(x1.y);
            t.u[6] = f2bf(x1.z); t.u[7] = f2bf(x1.w);
            af[kc] = t.v;
        }

        f32x4 acc[4];
        #pragma unroll
        for (int nt = 0; nt < 4; ++nt) acc[nt] = (f32x4){0.f, 0.f, 0.f, 0.f};
        #pragma unroll
        for (int kc = 0; kc < 4; ++kc) {
            #pragma unroll
            for (int nt = 0; nt < 4; ++nt)
                acc[nt] = __builtin_amdgcn_mfma_f32_16x16x32_bf16(
                    af[kc], wb[kc][nt], acc[nt], 0, 0, 0);
        }

        // epilogue: +bias, per-row absmax, biased-uint8 quantize
        // C/D layout: channel nt*16+col, row quad*4+reg
        float v[4][4];   // [nt][r]
        #pragma unroll
        for (int nt = 0; nt < 4; ++nt)
            #pragma unroll
            for (int r = 0; r < 4; ++r)
                v[nt][r] = acc[nt][r] + bcol[nt];

        float rmax[4];
        #pragma unroll
        for (int r = 0; r < 4; ++r) {
            float m = fabsf(v[0][r]);
            m = fmaxf(m, fabsf(v[1][r]));
            m = fmaxf(m, fabsf(v[2][r]));
            m = fmaxf(m, fabsf(v[3][r]));
            m = fmaxf(m, __shfl_xor(m, 1, 64));
            m = fmaxf(m, __shfl_xor(m, 2, 64));
            m = fmaxf(m, __shfl_xor(m, 4, 64));
            m = fmaxf(m, __shfl_xor(m, 8, 64));
            rmax[r] = m;
        }
        if (col < 4)
            Hs[r0 + quad * 4 + col] = rmax[col] * (1.f / 127.f);

        #pragma unroll
        for (int r = 0; r < 4; ++r) {
            const float inv = rmax[r] > 0.f ? 127.f / rmax[r] : 0.f;
            const unsigned u0 = (unsigned)(int)rintf(v[0][r] * inv + 128.f);
            const unsigned u1 = (unsigned)(int)rintf(v[1][r] * inv + 128.f);
            const unsigned u2 = (unsigned)(int)rintf(v[2][r] * inv + 128.f);
            const unsigned u3 = (unsigned)(int)rintf(v[3][r] * inv + 128.f);
            cl[(quad * 4 + r) * 20 + col] =
                u0 | (u1 << 8) | (u2 << 16) | (u3 << 24);
        }

        // transpose readback (wave-private LDS region, no barrier needed):
        // 64B row stores
        {
            const int row = lane >> 2;
            const int seg = lane & 3;
            const uint4 vv = *(const uint4*)(cl + row * 20 + seg * 4);
            H[(size_t)(r0 + row) * 4 + seg] = vv;
        }
    }
}

// ---------------------------------------------------------------------------
// Kernel 2/3: one propagation round on int8 per-row-scale rows (64B/row).
// Unchanged from R7 (at the ~3.4 TB/s LLC random-line ceiling: 800K edges x
// one 128B line each ~ 102MB line traffic/round ~ 28-30us).
// ---------------------------------------------------------------------------
#define ACC16(vv, c)                                                        \
    {                                                                        \
        const unsigned* _w = (const unsigned*)&(vv);                         \
        _Pragma("unroll")                                                    \
        for (int _d = 0; _d < 4; ++_d) {                                     \
            _Pragma("unroll")                                                \
            for (int _b = 0; _b < 4; ++_b)                                   \
                acc[_d * 4 + _b] = fmaf(                                     \
                    (float)((_w[_d] >> (8 * _b)) & 255u), (c), acc[_d*4+_b]);\
        }                                                                    \
    }

template <bool FINAL>
__global__ __launch_bounds__(256) void prop_kernel(
    const uint4* __restrict__ inq, const float* __restrict__ insc,
    void* __restrict__ outp, float* __restrict__ outsc,
    const int* __restrict__ rowptr, const int* __restrict__ src)
{
    const int tid   = threadIdx.x;
    const int lane  = tid & 63;
    const int s     = lane & 3;     // 16B chunk (dwords s*4..s*4+3)
    const int lbase = lane & 60;    // subgroup base lane
    const int noder = blockIdx.x * 64 + (tid >> 2);
    const bool valid = noder < N_NODES;
    const int node  = valid ? noder : N_NODES - 1;

    const int start = rowptr[node];
    const int end   = rowptr[node + 1];
    const int deg   = end - start;

    const uint4 ownq = inq[(size_t)node * 4 + s];
    const float owns = insc[node];

    float acc[16];
    #pragma unroll
    for (int k = 0; k < 16; ++k) acc[k] = 0.f;
    float sumS = 0.f;

    if (deg > 0) {
        for (int base = start; base < end; base += 8) {
            const int rem = end - base;
            const int liA = base + s;
            const int svA = src[liA < end ? liA : base];
            int svB = 0;
            if (base + 4 < end) {
                const int liB = base + 4 + s;
                svB = src[liB < end ? liB : base + 4];
            }
            const int e0 = __shfl(svA, lbase + 0, 64);
            const int e1 = __shfl(svA, lbase + 1, 64);
            const int e2 = __shfl(svA, lbase + 2, 64);
            const int e3 = __shfl(svA, lbase + 3, 64);
            const int e4 = __shfl(svB, lbase + 0, 64);
            const int e5 = __shfl(svB, lbase + 1, 64);
            const int e6 = __shfl(svB, lbase + 2, 64);
            const int e7 = __shfl(svB, lbase + 3, 64);

            const int i1 = rem > 1 ? e1 : e0;
            const int i2 = rem > 2 ? e2 : e0;
            const int i3 = rem > 3 ? e3 : e0;
            const int i4 = rem > 4 ? e4 : e0;
            const int i5 = rem > 5 ? e5 : e0;
            const int i6 = rem > 6 ? e6 : e0;
            const int i7 = rem > 7 ? e7 : e0;

            const uint4 v0 = inq[(size_t)e0 * 4 + s];
            const uint4 v1 = inq[(size_t)i1 * 4 + s];
            const uint4 v2 = inq[(size_t)i2 * 4 + s];
            const uint4 v3 = inq[(size_t)i3 * 4 + s];
            const uint4 v4 = inq[(size_t)i4 * 4 + s];
            const uint4 v5 = inq[(size_t)i5 * 4 + s];
            const uint4 v6 = inq[(size_t)i6 * 4 + s];
            const uint4 v7 = inq[(size_t)i7 * 4 + s];

            const float c0 = insc[e0];
            const float c1 = rem > 1 ? insc[i1] : 0.f;
            const float c2 = rem > 2 ? insc[i2] : 0.f;
            const float c3 = rem > 3 ? insc[i3] : 0.f;
            const float c4 = rem > 4 ? insc[i4] : 0.f;
            const float c5 = rem > 5 ? insc[i5] : 0.f;
            const float c6 = rem > 6 ? insc[i6] : 0.f;
            const float c7 = rem > 7 ? insc[i7] : 0.f;

            sumS += c0 + c1 + c2 + c3 + c4 + c5 + c6 + c7;
            ACC16(v0, c0); ACC16(v1, c1); ACC16(v2, c2); ACC16(v3, c3);
            ACC16(v4, c4); ACC16(v5, c5); ACC16(v6, c6); ACC16(v7, c7);
        }
        // own contribution
        ACC16(ownq, owns);
        sumS += owns;
    }

    float val[16];
    if (deg == 0) {
        #pragma unroll
        for (int k = 0; k < 16; ++k) val[k] = 0.f;
    } else {
        const float invm  = 1.0f / (float)(deg + 1);
        const float bias  = 128.f * sumS;
        #pragma unroll
        for (int k = 0; k < 16; ++k) {
            val[k] = (acc[k] - bias) * invm;
            if (FINAL) val[k] = fmaxf(val[k], 0.f);
        }
    }

    if (FINAL) {
        // un-permute: channel of val[d*4+b] is (s*4+d) + 16*b
        __shared__ float T[64 * 68];
        const int nl = tid >> 2;
        #pragma unroll
        for (int d = 0; d < 4; ++d)
            #pragma unroll
            for (int bb = 0; bb < 4; ++bb)
                T[nl * 68 + (s * 4 + d) + 16 * bb] = val[d * 4 + bb];
        __syncthreads();
        float* out = (float*)outp;
        const int nb = blockIdx.x * 64;
        #pragma unroll
        for (int p = 0; p < 4; ++p) {
            const int pos = p * 1024 + tid * 4;  // dword index in 64x64 tile
            const int n   = pos >> 6;
            const int ch  = pos & 63;
            if (nb + n < N_NODES) {
                const float4 vv = *(const float4*)(T + n * 68 + ch);
                *(float4*)(out + (size_t)(nb + n) * OUT_SIZE + ch) = vv;
            }
        }
    } else {
        // requantize: row absmax across 16 in-lane + 4-lane subgroup
        float m = 0.f;
        #pragma unroll
        for (int k = 0; k < 16; ++k) m = fmaxf(m, fabsf(val[k]));
        m = fmaxf(m, __shfl_xor(m, 1, 64));
        m = fmaxf(m, __shfl_xor(m, 2, 64));
        const float invq = m > 0.f ? 127.f / m : 0.f;
        uint4 pv;
        unsigned* pw = (unsigned*)&pv;
        #pragma unroll
        for (int d = 0; d < 4; ++d) {
            const unsigned u0 = (unsigned)(int)rintf(val[d * 4 + 0] * invq + 128.f);
            const unsigned u1 = (unsigned)(int)rintf(val[d * 4 + 1] * invq + 128.f);
            const unsigned u2 = (unsigned)(int)rintf(val[d * 4 + 2] * invq + 128.f);
            const unsigned u3 = (unsigned)(int)rintf(val[d * 4 + 3] * invq + 128.f);
            pw[d] = u0 | (u1 << 8) | (u2 << 16) | (u3 << 24);
        }
        if (valid) {
            ((uint4*)outp)[(size_t)node * 4 + s] = pv;
            if (s == 0) outsc[node] = m * (1.f / 127.f);
        }
    }
}

// ---------------------------------------------------------------------------
// Launch
// ---------------------------------------------------------------------------
extern "C" void kernel_launch(void* const* d_in, const int* in_sizes, int n_in,
                              void* d_out, int out_size, void* d_ws, size_t ws_size,
                              hipStream_t stream)
{
    const float* data = (const float*)d_in[0];
    const float* W    = (const float*)d_in[1];
    const float* b    = (const float*)d_in[2];
    const int*   src  = (const int*)d_in[3];
    const int*   tgt  = (const int*)d_in[4];

    // ws: H0 int8 (6.4MB) | H1 int8 (6.4MB) | H0s | H1s | rowptr
    char*  base   = (char*)d_ws;
    uint4* H0     = (uint4*)base;
    uint4* H1     = (uint4*)(base + (size_t)N_NODES * OUT_SIZE);
    float* H0s    = (float*)(base + 2 * (size_t)N_NODES * OUT_SIZE);
    float* H1s    = H0s + N_NODES;
    int*   rowptr = (int*)(H1s + N_NODES);

    gemm_rowptr_kernel<<<GEMM_BLOCKS + RP_BLOCKS, 256, 0, stream>>>(
        data, W, b, tgt, H0, H0s, rowptr);
    prop_kernel<false><<<PROP_BLOCKS, 256, 0, stream>>>(
        H0, H0s, (void*)H1, H1s, rowptr, src);
    prop_kernel<true ><<<PROP_BLOCKS, 256, 0, stream>>>(
        H1, H1s, d_out, nullptr, rowptr, src);
}

// Round 11
// 142.827 us; speedup vs baseline: 1.0879x; 1.0832x over previous
//
#include <hip/hip_runtime.h>

#define N_NODES 100000
#define N_EDGES 800000
#define IN_SIZE 128
#define OUT_SIZE 64

#define RP_BLOCKS   ((N_EDGES + 255) / 256)   // 3125 boundary-detect blocks, FIRST
#define GEMM_BLOCKS 1024                      // 4 blocks/CU
#define N_TILES     (N_NODES / 16)            // 6250 exact
#define PROP_BLOCKS ((N_NODES + 63) / 64)     // 64 nodes/block, 4 lanes/node
#define WS 136   // Wt LDS stride in bf16 elements (272B rows, 16B-aligned)

typedef __attribute__((ext_vector_type(8))) short short8;
typedef __attribute__((ext_vector_type(4))) float f32x4;

__device__ __forceinline__ unsigned short f2bf(float x) {
    unsigned u = __float_as_uint(x);
    u += 0x7FFFu + ((u >> 16) & 1u);          // round-to-nearest-even
    return (unsigned short)(u >> 16);
}
__device__ __forceinline__ unsigned pack2(float lo, float hi) {
    return (unsigned)f2bf(lo) | ((unsigned)f2bf(hi) << 16);
}

// int8 row layout (both H buffers): row = 16 dwords; dword d's byte b holds
// channel (d + 16*b), stored BIASED (u = q + 128). Per-row fp32 dequant
// scale in a separate array: val = scale * (u - 128).

// ---------------------------------------------------------------------------
// Kernel 1 (fused): CSR rowptr (boundary-detect scatter, blocks FIRST) +
// H0 = int8_rowscale(data @ W + b) via MFMA.
// R11 fix (evidence: dispatch pinned at ~41us since R4 with near-zero
// VALU/MFMA/occupancy regardless of gemm structure): the old rowptr built
// 100K binary searches = 20-deep chains of DEPENDENT random loads into cold
// tgt with only 128 blocks of TLP -> it was the dispatch straggler.
// New rowptr: thread per edge reads adjacent tgt[e-1],tgt[e] (coalesced
// 3.2MB stream, no dependent chains) and fills rowptr[t]=e for
// t in (tgt[e-1], tgt[e]]  (rowptr[t] = first edge with tgt >= t).
// ---------------------------------------------------------------------------
__global__ __launch_bounds__(256) void gemm_rowptr_kernel(
    const float* __restrict__ data, const float* __restrict__ W,
    const float* __restrict__ b, const int* __restrict__ tgt,
    uint4* __restrict__ H, float* __restrict__ Hs, int* __restrict__ rowptr)
{
    if (blockIdx.x < RP_BLOCKS) {
        const int e = (int)blockIdx.x * 256 + (int)threadIdx.x;
        if (e < N_EDGES) {
            const int bb = tgt[e];
            const int a  = (e == 0) ? -1 : tgt[e - 1];
            for (int t = a + 1; t <= bb; ++t) rowptr[t] = e;
            if (e == N_EDGES - 1)
                for (int t = bb + 1; t <= N_NODES; ++t) rowptr[t] = N_EDGES;
        }
        return;
    }

    __shared__ __align__(16) unsigned short Wt[64 * WS];  // 17408 B
    __shared__ unsigned Clds[4][16 * 20];                 //  5120 B

    const int tid  = threadIdx.x;
    const int lane = tid & 63;
    const int wv   = tid >> 6;
    const int quad = lane >> 4;
    const int col  = lane & 15;

    // ---- stage W (fp32 row-major [k][n]) -> LDS bf16 transposed Wt[n][k] ----
    {
        const int p = tid & 63;
        const int h = tid >> 6;
        const float* w0 = W + (size_t)(2 * p) * OUT_SIZE + h * 16;
        const float* w1 = w0 + OUT_SIZE;
        unsigned* Wt32 = (unsigned*)Wt;
        #pragma unroll
        for (int i = 0; i < 16; ++i)
            Wt32[(h * 16 + i) * (WS / 2) + p] = pack2(w0[i], w1[i]);
    }
    __syncthreads();

    float bcol[4];
    #pragma unroll
    for (int nt = 0; nt < 4; ++nt) bcol[nt] = b[nt * 16 + col];

    // ---- W fragments from LDS: one ds_read_b128 each ----
    short8 wb[4][4];
    #pragma unroll
    for (int kc = 0; kc < 4; ++kc)
        #pragma unroll
        for (int nt = 0; nt < 4; ++nt)
            wb[kc][nt] = *(const short8*)(
                Wt + (nt * 16 + col) * WS + kc * 32 + quad * 8);

    union U8 { short8 v; unsigned short u[8]; };
    unsigned* cl = Clds[wv];

    for (int tile = ((int)blockIdx.x - RP_BLOCKS) * 4 + wv; tile < N_TILES;
         tile += GEMM_BLOCKS * 4) {
        const int r0 = tile * 16;
        const float* arow = data + (size_t)(r0 + col) * IN_SIZE + quad * 8;

        short8 af[4];
        #pragma unroll
        for (int kc = 0; kc < 4; ++kc) {
            const float4 x0 = *(const float4*)(arow + kc * 32);
            const float4 x1 = *(const float4*)(arow + kc * 32 + 4);
            U8 t;
            t.u[0] = f2bf(x0.x); t.u[1] = f2bf(x0.y);
            t.u[2] = f2bf(x0.z); t.u[3] = f2bf(x0.w);
            t.u[4] = f2bf(x1.x); t.u[5] = f2bf(x1.y);
            t.u[6] = f2bf(x1.z); t.u[7] = f2bf(x1.w);
            af[kc] = t.v;
        }

        f32x4 acc[4];
        #pragma unroll
        for (int nt = 0; nt < 4; ++nt) acc[nt] = (f32x4){0.f, 0.f, 0.f, 0.f};
        #pragma unroll
        for (int kc = 0; kc < 4; ++kc) {
            #pragma unroll
            for (int nt = 0; nt < 4; ++nt)
                acc[nt] = __builtin_amdgcn_mfma_f32_16x16x32_bf16(
                    af[kc], wb[kc][nt], acc[nt], 0, 0, 0);
        }

        // epilogue: +bias, per-row absmax, biased-uint8 quantize
        // C/D layout: channel nt*16+col, row quad*4+reg
        float v[4][4];   // [nt][r]
        #pragma unroll
        for (int nt = 0; nt < 4; ++nt)
            #pragma unroll
            for (int r = 0; r < 4; ++r)
                v[nt][r] = acc[nt][r] + bcol[nt];

        float rmax[4];
        #pragma unroll
        for (int r = 0; r < 4; ++r) {
            float m = fabsf(v[0][r]);
            m = fmaxf(m, fabsf(v[1][r]));
            m = fmaxf(m, fabsf(v[2][r]));
            m = fmaxf(m, fabsf(v[3][r]));
            m = fmaxf(m, __shfl_xor(m, 1, 64));
            m = fmaxf(m, __shfl_xor(m, 2, 64));
            m = fmaxf(m, __shfl_xor(m, 4, 64));
            m = fmaxf(m, __shfl_xor(m, 8, 64));
            rmax[r] = m;
        }
        if (col < 4)
            Hs[r0 + quad * 4 + col] = rmax[col] * (1.f / 127.f);

        #pragma unroll
        for (int r = 0; r < 4; ++r) {
            const float inv = rmax[r] > 0.f ? 127.f / rmax[r] : 0.f;
            const unsigned u0 = (unsigned)(int)rintf(v[0][r] * inv + 128.f);
            const unsigned u1 = (unsigned)(int)rintf(v[1][r] * inv + 128.f);
            const unsigned u2 = (unsigned)(int)rintf(v[2][r] * inv + 128.f);
            const unsigned u3 = (unsigned)(int)rintf(v[3][r] * inv + 128.f);
            cl[(quad * 4 + r) * 20 + col] =
                u0 | (u1 << 8) | (u2 << 16) | (u3 << 24);
        }

        // transpose readback (wave-private LDS region, no barrier needed):
        // 64B row stores
        {
            const int row = lane >> 2;
            const int seg = lane & 3;
            const uint4 vv = *(const uint4*)(cl + row * 20 + seg * 4);
            H[(size_t)(r0 + row) * 4 + seg] = vv;
        }
    }
}

// ---------------------------------------------------------------------------
// Kernel 2/3: one propagation round on int8 per-row-scale rows (64B/row).
// Unchanged from R7 (at the ~3.4 TB/s LLC random-line ceiling: 800K edges x
// one 128B line each ~ 102MB line traffic/round).
// ---------------------------------------------------------------------------
#define ACC16(vv, c)                                                        \
    {                                                                        \
        const unsigned* _w = (const unsigned*)&(vv);                         \
        _Pragma("unroll")                                                    \
        for (int _d = 0; _d < 4; ++_d) {                                     \
            _Pragma("unroll")                                                \
            for (int _b = 0; _b < 4; ++_b)                                   \
                acc[_d * 4 + _b] = fmaf(                                     \
                    (float)((_w[_d] >> (8 * _b)) & 255u), (c), acc[_d*4+_b]);\
        }                                                                    \
    }

template <bool FINAL>
__global__ __launch_bounds__(256) void prop_kernel(
    const uint4* __restrict__ inq, const float* __restrict__ insc,
    void* __restrict__ outp, float* __restrict__ outsc,
    const int* __restrict__ rowptr, const int* __restrict__ src)
{
    const int tid   = threadIdx.x;
    const int lane  = tid & 63;
    const int s     = lane & 3;     // 16B chunk (dwords s*4..s*4+3)
    const int lbase = lane & 60;    // subgroup base lane
    const int noder = blockIdx.x * 64 + (tid >> 2);
    const bool valid = noder < N_NODES;
    const int node  = valid ? noder : N_NODES - 1;

    const int start = rowptr[node];
    const int end   = rowptr[node + 1];
    const int deg   = end - start;

    const uint4 ownq = inq[(size_t)node * 4 + s];
    const float owns = insc[node];

    float acc[16];
    #pragma unroll
    for (int k = 0; k < 16; ++k) acc[k] = 0.f;
    float sumS = 0.f;

    if (deg > 0) {
        for (int base = start; base < end; base += 8) {
            const int rem = end - base;
            const int liA = base + s;
            const int svA = src[liA < end ? liA : base];
            int svB = 0;
            if (base + 4 < end) {
                const int liB = base + 4 + s;
                svB = src[liB < end ? liB : base + 4];
            }
            const int e0 = __shfl(svA, lbase + 0, 64);
            const int e1 = __shfl(svA, lbase + 1, 64);
            const int e2 = __shfl(svA, lbase + 2, 64);
            const int e3 = __shfl(svA, lbase + 3, 64);
            const int e4 = __shfl(svB, lbase + 0, 64);
            const int e5 = __shfl(svB, lbase + 1, 64);
            const int e6 = __shfl(svB, lbase + 2, 64);
            const int e7 = __shfl(svB, lbase + 3, 64);

            const int i1 = rem > 1 ? e1 : e0;
            const int i2 = rem > 2 ? e2 : e0;
            const int i3 = rem > 3 ? e3 : e0;
            const int i4 = rem > 4 ? e4 : e0;
            const int i5 = rem > 5 ? e5 : e0;
            const int i6 = rem > 6 ? e6 : e0;
            const int i7 = rem > 7 ? e7 : e0;

            const uint4 v0 = inq[(size_t)e0 * 4 + s];
            const uint4 v1 = inq[(size_t)i1 * 4 + s];
            const uint4 v2 = inq[(size_t)i2 * 4 + s];
            const uint4 v3 = inq[(size_t)i3 * 4 + s];
            const uint4 v4 = inq[(size_t)i4 * 4 + s];
            const uint4 v5 = inq[(size_t)i5 * 4 + s];
            const uint4 v6 = inq[(size_t)i6 * 4 + s];
            const uint4 v7 = inq[(size_t)i7 * 4 + s];

            const float c0 = insc[e0];
            const float c1 = rem > 1 ? insc[i1] : 0.f;
            const float c2 = rem > 2 ? insc[i2] : 0.f;
            const float c3 = rem > 3 ? insc[i3] : 0.f;
            const float c4 = rem > 4 ? insc[i4] : 0.f;
            const float c5 = rem > 5 ? insc[i5] : 0.f;
            const float c6 = rem > 6 ? insc[i6] : 0.f;
            const float c7 = rem > 7 ? insc[i7] : 0.f;

            sumS += c0 + c1 + c2 + c3 + c4 + c5 + c6 + c7;
            ACC16(v0, c0); ACC16(v1, c1); ACC16(v2, c2); ACC16(v3, c3);
            ACC16(v4, c4); ACC16(v5, c5); ACC16(v6, c6); ACC16(v7, c7);
        }
        // own contribution
        ACC16(ownq, owns);
        sumS += owns;
    }

    float val[16];
    if (deg == 0) {
        #pragma unroll
        for (int k = 0; k < 16; ++k) val[k] = 0.f;
    } else {
        const float invm  = 1.0f / (float)(deg + 1);
        const float bias  = 128.f * sumS;
        #pragma unroll
        for (int k = 0; k < 16; ++k) {
            val[k] = (acc[k] - bias) * invm;
            if (FINAL) val[k] = fmaxf(val[k], 0.f);
        }
    }

    if (FINAL) {
        // un-permute: channel of val[d*4+b] is (s*4+d) + 16*b
        __shared__ float T[64 * 68];
        const int nl = tid >> 2;
        #pragma unroll
        for (int d = 0; d < 4; ++d)
            #pragma unroll
            for (int bb = 0; bb < 4; ++bb)
                T[nl * 68 + (s * 4 + d) + 16 * bb] = val[d * 4 + bb];
        __syncthreads();
        float* out = (float*)outp;
        const int nb = blockIdx.x * 64;
        #pragma unroll
        for (int p = 0; p < 4; ++p) {
            const int pos = p * 1024 + tid * 4;  // dword index in 64x64 tile
            const int n   = pos >> 6;
            const int ch  = pos & 63;
            if (nb + n < N_NODES) {
                const float4 vv = *(const float4*)(T + n * 68 + ch);
                *(float4*)(out + (size_t)(nb + n) * OUT_SIZE + ch) = vv;
            }
        }
    } else {
        // requantize: row absmax across 16 in-lane + 4-lane subgroup
        float m = 0.f;
        #pragma unroll
        for (int k = 0; k < 16; ++k) m = fmaxf(m, fabsf(val[k]));
        m = fmaxf(m, __shfl_xor(m, 1, 64));
        m = fmaxf(m, __shfl_xor(m, 2, 64));
        const float invq = m > 0.f ? 127.f / m : 0.f;
        uint4 pv;
        unsigned* pw = (unsigned*)&pv;
        #pragma unroll
        for (int d = 0; d < 4; ++d) {
            const unsigned u0 = (unsigned)(int)rintf(val[d * 4 + 0] * invq + 128.f);
            const unsigned u1 = (unsigned)(int)rintf(val[d * 4 + 1] * invq + 128.f);
            const unsigned u2 = (unsigned)(int)rintf(val[d * 4 + 2] * invq + 128.f);
            const unsigned u3 = (unsigned)(int)rintf(val[d * 4 + 3] * invq + 128.f);
            pw[d] = u0 | (u1 << 8) | (u2 << 16) | (u3 << 24);
        }
        if (valid) {
            ((uint4*)outp)[(size_t)node * 4 + s] = pv;
            if (s == 0) outsc[node] = m * (1.f / 127.f);
        }
    }
}

// ---------------------------------------------------------------------------
// Launch
// ---------------------------------------------------------------------------
extern "C" void kernel_launch(void* const* d_in, const int* in_sizes, int n_in,
                              void* d_out, int out_size, void* d_ws, size_t ws_size,
                              hipStream_t stream)
{
    const float* data = (const float*)d_in[0];
    const float* W    = (const float*)d_in[1];
    const float* b    = (const float*)d_in[2];
    const int*   src  = (const int*)d_in[3];
    const int*   tgt  = (const int*)d_in[4];

    // ws: H0 int8 (6.4MB) | H1 int8 (6.4MB) | H0s | H1s | rowptr
    char*  base   = (char*)d_ws;
    uint4* H0     = (uint4*)base;
    uint4* H1     = (uint4*)(base + (size_t)N_NODES * OUT_SIZE);
    float* H0s    = (float*)(base + 2 * (size_t)N_NODES * OUT_SIZE);
    float* H1s    = H0s + N_NODES;
    int*   rowptr = (int*)(H1s + N_NODES);

    gemm_rowptr_kernel<<<RP_BLOCKS + GEMM_BLOCKS, 256, 0, stream>>>(
        data, W, b, tgt, H0, H0s, rowptr);
    prop_kernel<false><<<PROP_BLOCKS, 256, 0, stream>>>(
        H0, H0s, (void*)H1, H1s, rowptr, src);
    prop_kernel<true ><<<PROP_BLOCKS, 256, 0, stream>>>(
        H1, H1s, d_out, nullptr, rowptr, src);
}